// Round 2
// baseline (78.032 us; speedup 1.0000x reference)
//
#include <hip/hip_runtime.h>
#include <math.h>

// Problem constants
#define NPRED 1024
#define NT 64
#define PD 85            // 5 + 80 classes
#define NLOGIT 79        // pred[:, 6:] -> 85-6 (reference quirk)
#define RPB 128          // pred rows per K1 block
#define K1_THREADS 256
#define K1_F4 ((RPB * PD) / 4)                              // 2720 float4 per block
#define K1_ITERS ((K1_F4 + K1_THREADS - 1) / K1_THREADS)    // 11

__device__ __forceinline__ float softplusf(float x) {
    return fmaxf(x, 0.0f) + log1pf(expf(-fabsf(x)));
}

// ------------------------------------------------------------------
// K1: stream preds coalesced -> LDS, per-pred best IoU / argmax,
//     write best/bidx arrays + per-block partials {max, any, sum softplus}
// grid = B*8 blocks of 256 threads; block (b, k) owns rows [k*128, k*128+128)
// ------------------------------------------------------------------
__global__ __launch_bounds__(K1_THREADS)
void k1_match(const float* __restrict__ preds,
              const float* __restrict__ targets,
              float* __restrict__ best_arr,
              int*   __restrict__ bidx_arr,
              float* __restrict__ pmax,
              float* __restrict__ psp,
              int*   __restrict__ pany)
{
    const int bx   = blockIdx.x;
    const int b    = bx >> 3;
    const int kblk = bx & 7;
    const int tid  = threadIdx.x;

    __shared__ float rows[RPB * PD];   // 43520 B
    __shared__ float tg[NT * 5];
    __shared__ float ta[NT];
    __shared__ int   tv[NT];
    __shared__ float pb[K1_THREADS];
    __shared__ int   pi[K1_THREADS];
    __shared__ float redf[4];
    __shared__ int   redi[4];
    __shared__ float reds[4];

    // ---- issue ALL global loads first (max MLP), then write LDS ----
    const float4* g4 = (const float4*)(preds + ((size_t)b * NPRED + (size_t)kblk * RPB) * PD);
    float4 tmp[K1_ITERS];
    #pragma unroll
    for (int i = 0; i < K1_ITERS; ++i) {
        int idx = tid + i * K1_THREADS;
        if (idx < K1_F4) tmp[i] = g4[idx];
    }
    float4 tgt_tmp;
    if (tid < (NT * 5 / 4)) tgt_tmp = ((const float4*)(targets + (size_t)b * NT * 5))[tid];

    float4* r4 = (float4*)rows;
    #pragma unroll
    for (int i = 0; i < K1_ITERS; ++i) {
        int idx = tid + i * K1_THREADS;
        if (idx < K1_F4) r4[idx] = tmp[i];
    }
    if (tid < (NT * 5 / 4)) ((float4*)tg)[tid] = tgt_tmp;
    __syncthreads();

    if (tid < NT) {
        float x1 = tg[tid*5], y1 = tg[tid*5+1], x2 = tg[tid*5+2], y2 = tg[tid*5+3], c = tg[tid*5+4];
        ta[tid] = (x2 - x1) * (y2 - y1);
        tv[tid] = (c >= 0.0f) ? 1 : 0;
    }
    __syncthreads();

    // ---- 2 threads per row: halves of the 64-target scan ----
    const int r = tid & (RPB - 1);
    const int h = tid >> 7;                 // wave-uniform (0 for waves 0-1, 1 for 2-3)
    const float px1 = rows[r*PD+0], py1 = rows[r*PD+1];
    const float px2 = rows[r*PD+2], py2 = rows[r*PD+3];
    const float parea = (px2 - px1) * (py2 - py1);

    float best = -INFINITY;
    int   bidx = h * 32;
    #pragma unroll 8
    for (int tl = 0; tl < 32; ++tl) {
        const int t = h * 32 + tl;
        float w  = fminf(px2, tg[t*5+2]) - fmaxf(px1, tg[t*5+0]); w  = fmaxf(w, 0.0f);
        float hh = fminf(py2, tg[t*5+3]) - fmaxf(py1, tg[t*5+1]); hh = fmaxf(hh, 0.0f);
        float inter = w * hh;
        float uni   = parea + ta[t] - inter;
        float iou   = tv[t] ? inter / (uni + 1e-6f) : -1.0f;
        if (iou > best) { best = iou; bidx = t; }   // strict > => first occurrence
    }
    pb[tid] = best; pi[tid] = bidx;
    __syncthreads();

    float fbest = -INFINITY;
    float sp = 0.0f;
    int mraw = 0;
    if (tid < RPB) {
        float bA = pb[tid], bB = pb[tid + RPB];
        int   iA = pi[tid], iB = pi[tid + RPB];
        fbest = (bA >= bB) ? bA : bB;            // tie -> lower index (half A)
        int fidx = (bA >= bB) ? iA : iB;
        best_arr[(size_t)b * NPRED + kblk * RPB + tid] = fbest;
        bidx_arr[(size_t)b * NPRED + kblk * RPB + tid] = fidx;
        mraw = (fbest > 0.5f) ? 1 : 0;
        sp = softplusf(rows[r * PD + 4]);
    }

    // ---- block partials: max(best), any(mraw), sum(softplus) over the 128 rows ----
    float vmax = fbest;
    #pragma unroll
    for (int o = 32; o > 0; o >>= 1) vmax = fmaxf(vmax, __shfl_down(vmax, o));
    float vsp = sp;
    #pragma unroll
    for (int o = 32; o > 0; o >>= 1) vsp += __shfl_down(vsp, o);
    unsigned long long bal = __ballot(mraw != 0);
    if ((tid & 63) == 0) {
        redf[tid >> 6] = vmax;
        reds[tid >> 6] = vsp;
        redi[tid >> 6] = (bal != 0ULL) ? 1 : 0;
    }
    __syncthreads();
    if (tid == 0) {
        float m = redf[0], s = reds[0]; int a = redi[0];
        #pragma unroll
        for (int i = 1; i < 4; ++i) { m = fmaxf(m, redf[i]); s += reds[i]; a |= redi[i]; }
        pmax[bx] = m; psp[bx] = s; pany[bx] = a;
    }
}

// ------------------------------------------------------------------
// K2: per-sample: combine partials, find matched set, compute loss.
// grid = B blocks of 256 threads, 4 preds/thread (coalesced best/bidx reads)
// ------------------------------------------------------------------
__device__ __forceinline__ float bsum256(float v, float* red) {
    const int tid = threadIdx.x;
    #pragma unroll
    for (int o = 32; o > 0; o >>= 1) v += __shfl_down(v, o);
    __syncthreads();
    if ((tid & 63) == 0) red[tid >> 6] = v;
    __syncthreads();
    return (tid == 0) ? (red[0] + red[1] + red[2] + red[3]) : 0.0f;
}

__global__ __launch_bounds__(256)
void k2_loss(const float* __restrict__ preds,
             const float* __restrict__ targets,
             const float* __restrict__ best_arr,
             const int*   __restrict__ bidx_arr,
             const float* __restrict__ pmax,
             const float* __restrict__ psp,
             const int*   __restrict__ pany,
             float* __restrict__ per_sample)
{
    const int b = blockIdx.x;
    const int tid = threadIdx.x;

    __shared__ float tg[NT * 5];
    __shared__ float red[4];
    __shared__ float p8[8], s8[8];
    __shared__ int   a8[8];
    __shared__ float gmax_s, sp_s;
    __shared__ int   any_s, kv_s;

    if (tid < (NT * 5 / 4))
        ((float4*)tg)[tid] = ((const float4*)(targets + (size_t)b * NT * 5))[tid];
    if (tid < 8) {
        p8[tid] = pmax[b * 8 + tid];
        s8[tid] = psp[b * 8 + tid];
        a8[tid] = pany[b * 8 + tid];
    }
    __syncthreads();
    if (tid == 0) {
        float m = p8[0], s = s8[0]; int a = a8[0];
        #pragma unroll
        for (int i = 1; i < 8; ++i) { m = fmaxf(m, p8[i]); s += s8[i]; a |= a8[i]; }
        gmax_s = m; sp_s = s; any_s = a;
        int kv = 0;
        #pragma unroll
        for (int t = 0; t < NT; ++t) kv += (tg[t*5+4] >= 0.0f) ? 1 : 0;
        kv_s = kv;
    }
    __syncthreads();

    const float gmax = gmax_s;
    const int   anym = any_s;

    const float4 bst = ((const float4*)best_arr)[(size_t)b * 256 + tid];
    const int4   bix = ((const int4*)bidx_arr)[(size_t)b * 256 + tid];

    float mcnt = 0.0f, bbox = 0.0f, ce = 0.0f, sfm = 0.0f, spm = 0.0f;
    #pragma unroll
    for (int k = 0; k < 4; ++k) {
        const float bk = (&bst.x)[k];
        const int   ik = (&bix.x)[k];
        const bool matched = anym ? (bk > 0.5f) : (bk == gmax);  // exact-equality ties, as in JAX
        if (matched) {
            const float* gp = preds + ((size_t)b * NPRED + tid * 4 + k) * PD;
            const float q0 = gp[0], q1 = gp[1], q2 = gp[2], q3 = gp[3], cf = gp[4];
            float dd[4] = { q0 - tg[ik*5+0], q1 - tg[ik*5+1], q2 - tg[ik*5+2], q3 - tg[ik*5+3] };
            #pragma unroll
            for (int i = 0; i < 4; ++i) {
                float ad = fabsf(dd[i]);
                bbox += (ad < 1.0f) ? 0.5f * dd[i] * dd[i] : ad - 0.5f;
            }
            float mx = -INFINITY;
            for (int i = 0; i < NLOGIT; ++i) mx = fmaxf(mx, gp[6 + i]);
            float s = 0.0f;
            for (int i = 0; i < NLOGIT; ++i) s += expf(gp[6 + i] - mx);
            const float lse = mx + logf(s);
            int label = (int)tg[ik*5+4];
            label = label < 0 ? 0 : (label > NLOGIT - 1 ? NLOGIT - 1 : label);
            ce  += lse - gp[6 + label];
            sfm += softplusf(-cf);
            spm += softplusf(cf);
            mcnt += 1.0f;
        }
    }

    const float mcnt_s = bsum256(mcnt, red);
    const float bbox_s = bsum256(bbox, red);
    const float ce_s   = bsum256(ce,   red);
    const float sfm_s  = bsum256(sfm,  red);
    const float spm_s  = bsum256(spm,  red);

    if (tid == 0) {
        const float sp_total = sp_s;
        const float ucnt = (float)NPRED - mcnt_s;
        const float sfu_s = sp_total - spm_s;   // sum softplus over unmatched
        const float bbox_loss = bbox_s / fmaxf(mcnt_s * 4.0f, 1.0f);
        const float cls_loss  = ce_s   / fmaxf(mcnt_s, 1.0f);
        const float conf_m    = sfm_s  / fmaxf(mcnt_s, 1.0f);
        const float conf_u    = sfu_s  / fmaxf(ucnt, 1.0f);
        const float conf_loss = (ucnt > 0.0f) ? (conf_m + conf_u) * 0.5f : conf_m;
        const float loss_valid   = bbox_loss + cls_loss + conf_loss;
        const float loss_novalid = sp_total / (float)NPRED;
        per_sample[b] = (kv_s > 0) ? loss_valid : loss_novalid;
    }
}

// ------------------------------------------------------------------
// K3: mean over per-sample losses
// ------------------------------------------------------------------
__global__ void k3_final(const float* __restrict__ per_sample,
                         float* __restrict__ out, int nb)
{
    const int tid = threadIdx.x;
    float v = 0.0f;
    for (int i = tid; i < nb; i += 128) v += per_sample[i];
    #pragma unroll
    for (int o = 32; o > 0; o >>= 1) v += __shfl_down(v, o);
    __shared__ float r[2];
    if ((tid & 63) == 0) r[tid >> 6] = v;
    __syncthreads();
    if (tid == 0) out[0] = (r[0] + r[1]) / (float)nb;
}

extern "C" void kernel_launch(void* const* d_in, const int* in_sizes, int n_in,
                              void* d_out, int out_size, void* d_ws, size_t ws_size,
                              hipStream_t stream) {
    const float* preds   = (const float*)d_in[0];
    const float* targets = (const float*)d_in[1];
    float* out = (float*)d_out;

    const int nb = in_sizes[0] / (NPRED * PD);   // B = 128

    // ws layout (floats)
    float* ws_f       = (float*)d_ws;
    float* best_arr   = ws_f;                        // nb*1024
    int*   bidx_arr   = (int*)(ws_f + (size_t)nb * NPRED);       // nb*1024
    float* pmax       = ws_f + (size_t)2 * nb * NPRED;           // nb*8
    float* psp        = pmax + (size_t)nb * 8;                   // nb*8
    int*   pany       = (int*)(psp + (size_t)nb * 8);            // nb*8
    float* per_sample = (float*)(pany + (size_t)nb * 8);         // nb

    hipLaunchKernelGGL(k1_match, dim3(nb * 8), dim3(K1_THREADS), 0, stream,
                       preds, targets, best_arr, bidx_arr, pmax, psp, pany);
    hipLaunchKernelGGL(k2_loss, dim3(nb), dim3(256), 0, stream,
                       preds, targets, best_arr, bidx_arr, pmax, psp, pany, per_sample);
    hipLaunchKernelGGL(k3_final, dim3(1), dim3(128), 0, stream,
                       per_sample, out, nb);
}

// Round 3
// 30.530 us; speedup vs baseline: 2.5559x; 2.5559x over previous
//
#include <hip/hip_runtime.h>
#include <math.h>

// Problem constants
#define NPRED 1024
#define NT 64
#define PD 85            // 5 + 80 classes
#define NLOGIT 79        // pred[:, 6:] -> 85-6 columns (reference quirk)
#define ROWS 256         // pred rows per K1 block
#define QBLK 4           // K1 blocks per sample

__device__ __forceinline__ float softplusf(float x) {
    return fmaxf(x, 0.0f) + log1pf(expf(-fabsf(x)));
}

// part[] array layout (each of size nblk):
//  0 sp   1 cntA 2 bboxA 3 ceA 4 sfmA 5 spmA
//  6 cntB 7 bboxB 8 ceB  9 sfmB 10 spmB
// 11 block_max   12 kv (per-sample, replicated per block)

__global__ __launch_bounds__(256)
void k1_match(const float* __restrict__ preds,
              const float* __restrict__ targets,
              float* __restrict__ part, int nblk)
{
    const int bx  = blockIdx.x;
    const int b   = bx >> 2;
    const int q   = bx & 3;
    const int tid = threadIdx.x;
    const int r   = q * ROWS + tid;          // pred row within sample

    __shared__ float tgs[NT * 5];
    __shared__ float tx1[NT], ty1[NT], tx2[NT], ty2[NT], tcl[NT], ta[NT];
    __shared__ int   tv[NT];
    __shared__ float red[4][11];
    __shared__ float redm[4];
    __shared__ float bmax_s;
    __shared__ int   kv_s;

    // ---- issue per-row pred loads early (5 independent dwords) ----
    const float* pp = preds + ((size_t)b * NPRED + r) * PD;
    const float px1 = pp[0], py1 = pp[1], px2 = pp[2], py2 = pp[3], conf = pp[4];

    // ---- stage targets (coalesced float4) ----
    if (tid < (NT * 5 / 4))
        ((float4*)tgs)[tid] = ((const float4*)(targets + (size_t)b * NT * 5))[tid];
    __syncthreads();
    if (tid < NT) {
        float a = tgs[tid*5], c = tgs[tid*5+1], d = tgs[tid*5+2], e = tgs[tid*5+3], f = tgs[tid*5+4];
        tx1[tid]=a; ty1[tid]=c; tx2[tid]=d; ty2[tid]=e; tcl[tid]=f;
        ta[tid] = (d - a) * (e - c);
        tv[tid] = (f >= 0.0f) ? 1 : 0;
        unsigned long long bl = __ballot(f >= 0.0f);   // wave 0, all 64 lanes active
        if (tid == 0) kv_s = (int)__popcll(bl);
    }
    __syncthreads();

    // ---- per-pred best IoU / first-argmax over 64 targets ----
    const float parea = (px2 - px1) * (py2 - py1);
    float best = -INFINITY;
    int   bidx = 0;
    #pragma unroll 8
    for (int t = 0; t < NT; ++t) {
        float w = fminf(px2, tx2[t]) - fmaxf(px1, tx1[t]); w = fmaxf(w, 0.0f);
        float h = fminf(py2, ty2[t]) - fmaxf(py1, ty1[t]); h = fmaxf(h, 0.0f);
        float inter = w * h;
        float uni   = parea + ta[t] - inter;
        float iou   = tv[t] ? inter / (uni + 1e-6f) : -1.0f;
        if (iou > best) { best = iou; bidx = t; }   // strict > => first occurrence (JAX argmax)
    }

    // ---- block max of best (needed before candidate pass) ----
    {
        float v = best;
        #pragma unroll
        for (int o = 32; o > 0; o >>= 1) v = fmaxf(v, __shfl_down(v, o));
        if ((tid & 63) == 0) redm[tid >> 6] = v;
        __syncthreads();
        if (tid == 0) bmax_s = fmaxf(fmaxf(redm[0], redm[1]), fmaxf(redm[2], redm[3]));
        __syncthreads();
    }
    const float bmax = bmax_s;
    const bool cA = (best > 0.5f);        // matched_raw
    const bool cB = (best == bmax);       // block-local argmax set (exact equality)

    const float sp = softplusf(conf);
    float vals[11];
    #pragma unroll
    for (int j = 0; j < 11; ++j) vals[j] = 0.0f;
    vals[0] = sp;

    if (cA || cB) {
        // smooth-L1 bbox vs matched target (LDS)
        float d0 = px1 - tx1[bidx], d1 = py1 - ty1[bidx];
        float d2 = px2 - tx2[bidx], d3 = py2 - ty2[bidx];
        float bb = 0.0f;
        {
            float dd[4] = { d0, d1, d2, d3 };
            #pragma unroll
            for (int i = 0; i < 4; ++i) {
                float ad = fabsf(dd[i]);
                bb += (ad < 1.0f) ? 0.5f * dd[i] * dd[i] : ad - 0.5f;
            }
        }
        // online logsumexp over 79 logits (single global pass, unrolled loads)
        const float* lg = pp + 6;
        float m = -INFINITY, s = 0.0f;
        #pragma unroll
        for (int i = 0; i < NLOGIT; ++i) {
            float v  = lg[i];
            float nm = fmaxf(m, v);
            s = s * expf(m - nm) + expf(v - nm);
            m = nm;
        }
        const float lse = m + logf(s);
        int label = (int)tcl[bidx];
        label = label < 0 ? 0 : (label > NLOGIT - 1 ? NLOGIT - 1 : label);
        const float cev = lse - pp[6 + label];
        const float sfm = softplusf(-conf);

        if (cA) { vals[1] += 1.0f; vals[2] += bb; vals[3] += cev; vals[4] += sfm; vals[5] += sp; }
        if (cB) { vals[6] += 1.0f; vals[7] += bb; vals[8] += cev; vals[9] += sfm; vals[10] += sp; }
    }

    // ---- block sums of the 11 values ----
    #pragma unroll
    for (int j = 0; j < 11; ++j) {
        float v = vals[j];
        #pragma unroll
        for (int o = 32; o > 0; o >>= 1) v += __shfl_down(v, o);
        if ((tid & 63) == 0) red[tid >> 6][j] = v;
    }
    __syncthreads();
    if (tid < 11)  part[(size_t)tid * nblk + bx] = red[0][tid] + red[1][tid] + red[2][tid] + red[3][tid];
    if (tid == 11) part[(size_t)11  * nblk + bx] = bmax;
    if (tid == 12) part[(size_t)12  * nblk + bx] = (float)kv_s;
}

// ------------------------------------------------------------------
// K2: one block; combine 4 partials/sample, per-sample loss, final mean.
// ------------------------------------------------------------------
__global__ __launch_bounds__(512)
void k2_final(const float* __restrict__ part, float* __restrict__ out,
              int nb, int nblk)
{
    const int t = threadIdx.x;
    const int s = t >> 2, k = t & 3;
    const int bx = s * 4 + k;

    __shared__ float ps[128];
    __shared__ float r2[2];

    float v[13];
    #pragma unroll
    for (int j = 0; j < 13; ++j) v[j] = part[(size_t)j * nblk + bx];

    // group-of-4 butterfly: gmax over block maxes
    float pmax_k = v[11];
    float gmax = pmax_k;
    gmax = fmaxf(gmax, __shfl_xor(gmax, 1));
    gmax = fmaxf(gmax, __shfl_xor(gmax, 2));
    // mask B contributions to blocks whose max equals the global max
    const float mB = (pmax_k == gmax) ? 1.0f : 0.0f;
    v[6] *= mB; v[7] *= mB; v[8] *= mB; v[9] *= mB; v[10] *= mB;
    // sum butterflies for the 11 accumulators
    #pragma unroll
    for (int j = 0; j < 11; ++j) {
        v[j] += __shfl_xor(v[j], 1);
        v[j] += __shfl_xor(v[j], 2);
    }

    if (k == 0) {
        const float sp_total = v[0];
        const bool  anym = (v[1] > 0.0f);
        const float mcnt = anym ? v[1] : v[6];
        const float bboxs = anym ? v[2] : v[7];
        const float ces   = anym ? v[3] : v[8];
        const float sfms  = anym ? v[4] : v[9];
        const float spms  = anym ? v[5] : v[10];
        const float ucnt = (float)NPRED - mcnt;
        const float sfus = sp_total - spms;     // softplus sum over unmatched
        const float bbox_loss = bboxs / fmaxf(mcnt * 4.0f, 1.0f);
        const float cls_loss  = ces   / fmaxf(mcnt, 1.0f);
        const float conf_m    = sfms  / fmaxf(mcnt, 1.0f);
        const float conf_u    = sfus  / fmaxf(ucnt, 1.0f);
        const float conf_loss = (ucnt > 0.0f) ? (conf_m + conf_u) * 0.5f : conf_m;
        const float loss_valid   = bbox_loss + cls_loss + conf_loss;
        const float loss_novalid = sp_total / (float)NPRED;
        const int   kv = (int)v[12];
        ps[s] = (kv > 0) ? loss_valid : loss_novalid;
    }
    __syncthreads();

    if (t < 128) {
        float x = (t < nb) ? ps[t] : 0.0f;
        #pragma unroll
        for (int o = 32; o > 0; o >>= 1) x += __shfl_down(x, o);
        if ((t & 63) == 0) r2[t >> 6] = x;
    }
    __syncthreads();
    if (t == 0) out[0] = (r2[0] + r2[1]) / (float)nb;
}

extern "C" void kernel_launch(void* const* d_in, const int* in_sizes, int n_in,
                              void* d_out, int out_size, void* d_ws, size_t ws_size,
                              hipStream_t stream) {
    const float* preds   = (const float*)d_in[0];
    const float* targets = (const float*)d_in[1];
    float* out  = (float*)d_out;
    float* part = (float*)d_ws;

    const int nb   = in_sizes[0] / (NPRED * PD);   // B = 128
    const int nblk = nb * QBLK;                    // 512

    hipLaunchKernelGGL(k1_match, dim3(nblk), dim3(ROWS), 0, stream,
                       preds, targets, part, nblk);
    hipLaunchKernelGGL(k2_final, dim3(1), dim3(nb * 4), 0, stream,
                       part, out, nb, nblk);
}